// Round 2
// baseline (461.641 us; speedup 1.0000x reference)
//
#include <hip/hip_runtime.h>
#include <math.h>

// Problem constants (match reference)
#define BB 8
#define AA 512
#define NBH 64
#define FF 128
#define GG 50
#define NH 8
#define DH 16
#define CUTOFF 5.0f

// One block per (b,a) atom. 256 threads = 4 waves.
// Thread identity: j = tid & 127 (feature/output column), nh = tid >> 7 (neighbor half).
// LDS nbhT stored [feature i][neighbor n] with row stride 68 floats:
//   - reads in k/v loop: all lanes read the same float4 (broadcast, conflict-free)
//   - writes (transposed): stride 68 -> 8-way bank conflict, one-time cost only.
__global__ __launch_bounds__(256, 2)
void tdt_kernel(const float* __restrict__ x,
                const float* __restrict__ r_ij,
                const float* __restrict__ f_ij,
                const float* __restrict__ W_filt,
                const float* __restrict__ b_filt,
                const float* __restrict__ Wq,
                const float* __restrict__ Wk,
                const float* __restrict__ Wv,
                const float* __restrict__ Wo,
                const float* __restrict__ bo,
                const int*   __restrict__ neighbors,
                const int*   __restrict__ nmask,  // jax bool -> int32 on device (harness contract)
                float* __restrict__ out)
{
    const int ba  = blockIdx.x;          // 0..4095
    const int b   = ba >> 9;             // / 512
    const int tid = threadIdx.x;
    const int j   = tid & 127;
    const int nh  = tid >> 7;            // 0 or 1
    const int nbase = nh * 32;

    __shared__ float f_sT[GG * 64];      // [g][n], stride 64
    __shared__ float nbhT[FF * 68];      // [i][n], stride 68
    __shared__ float C_s[NBH];
    __shared__ int   nbr_s[NBH];
    __shared__ int   mask_s[NBH];
    __shared__ float x_s[FF];
    __shared__ float qpart[2 * FF];
    __shared__ float q_s[FF];
    __shared__ float scores_s[NH * NBH]; // reused in-place for attn
    __shared__ float msg_part[2 * FF];
    __shared__ float msg_s[FF];
    __shared__ float opart[2 * FF];

    const float*  xb   = x + (size_t)b * AA * FF;
    const size_t  bao  = (size_t)ba;

    // ---------------- phase 0: cooperative loads ----------------
    if (tid < FF) x_s[tid] = x[bao * FF + tid];
    if (tid < NBH) {
        float r = r_ij[bao * NBH + tid];
        float c = 0.5f * (cosf((float)M_PI * r * (1.0f / CUTOFF)) + 1.0f);
        C_s[tid]    = (r < CUTOFF) ? c : 0.0f;
        nbr_s[tid]  = neighbors[bao * NBH + tid];
        mask_s[tid] = nmask[bao * NBH + tid];
    }
    {
        const float* frow = f_ij + bao * (size_t)(NBH * GG);
        for (int idx = tid; idx < NBH * GG; idx += 256) {
            int n = idx / GG;
            int g = idx - n * GG;
            f_sT[g * 64 + n] = frow[idx];
        }
    }
    __syncthreads();

    // ---------------- phase 1: filter net + gather -> nbhT; q partial ----------------
    {
        float bf = b_filt[j];
        float wacc[32];
#pragma unroll
        for (int n = 0; n < 32; ++n) wacc[n] = bf;

#pragma unroll 2
        for (int g = 0; g < GG; ++g) {
            float wf = W_filt[g * FF + j];
            const float4* fr = (const float4*)&f_sT[g * 64 + nbase];
#pragma unroll
            for (int q4 = 0; q4 < 8; ++q4) {
                float4 fv = fr[q4];
                wacc[q4 * 4 + 0] = fmaf(fv.x, wf, wacc[q4 * 4 + 0]);
                wacc[q4 * 4 + 1] = fmaf(fv.y, wf, wacc[q4 * 4 + 1]);
                wacc[q4 * 4 + 2] = fmaf(fv.z, wf, wacc[q4 * 4 + 2]);
                wacc[q4 * 4 + 3] = fmaf(fv.w, wf, wacc[q4 * 4 + 3]);
            }
        }
        // gather neighbor features, modulate, write transposed
#pragma unroll 8
        for (int n = 0; n < 32; ++n) {
            int   ng = nbase + n;
            float xv = xb[(size_t)nbr_s[ng] * FF + j];
            nbhT[j * 68 + ng] = wacc[n] * C_s[ng] * xv;
        }
    }
    {
        float qp = 0.0f;
        int   i0 = nh * 64;
#pragma unroll 4
        for (int i = 0; i < 64; ++i) {
            int ii = i0 + i;
            qp = fmaf(x_s[ii], Wq[ii * FF + j], qp);
        }
        qpart[nh * FF + j] = qp;
    }
    __syncthreads();

    // ---------------- phase 2: q combine + k/v projections (register tile) ----------------
    if (tid < FF) q_s[tid] = qpart[tid] + qpart[FF + tid];

    float kacc[32], vacc[32];
#pragma unroll
    for (int n = 0; n < 32; ++n) { kacc[n] = 0.0f; vacc[n] = 0.0f; }

#pragma unroll 2
    for (int i = 0; i < FF; ++i) {
        float wk = Wk[i * FF + j];
        float wv = Wv[i * FF + j];
        const float4* nr = (const float4*)&nbhT[i * 68 + nbase];
#pragma unroll
        for (int q4 = 0; q4 < 8; ++q4) {
            float4 nb = nr[q4];
            kacc[q4 * 4 + 0] = fmaf(nb.x, wk, kacc[q4 * 4 + 0]);
            kacc[q4 * 4 + 1] = fmaf(nb.y, wk, kacc[q4 * 4 + 1]);
            kacc[q4 * 4 + 2] = fmaf(nb.z, wk, kacc[q4 * 4 + 2]);
            kacc[q4 * 4 + 3] = fmaf(nb.w, wk, kacc[q4 * 4 + 3]);
            vacc[q4 * 4 + 0] = fmaf(nb.x, wv, vacc[q4 * 4 + 0]);
            vacc[q4 * 4 + 1] = fmaf(nb.y, wv, vacc[q4 * 4 + 1]);
            vacc[q4 * 4 + 2] = fmaf(nb.z, wv, vacc[q4 * 4 + 2]);
            vacc[q4 * 4 + 3] = fmaf(nb.w, wv, vacc[q4 * 4 + 3]);
        }
    }
    __syncthreads();   // q_s visible to all

    // ---------------- phase 3: scores = q . k (shuffle-reduce over 16 lanes) ----------------
    {
        float qv   = q_s[j];
        int   head = j >> 4;
#pragma unroll
        for (int n = 0; n < 32; ++n) {
            float s = qv * kacc[n];
            s += __shfl_xor(s, 1, 64);
            s += __shfl_xor(s, 2, 64);
            s += __shfl_xor(s, 4, 64);
            s += __shfl_xor(s, 8, 64);
            if ((j & 15) == 0) {
                int   ng = nbase + n;
                float sc = s * 0.25f;            // 1/sqrt(16)
                if (!mask_s[ng]) sc = -1e9f;
                scores_s[head * NBH + ng] = sc;
            }
        }
    }
    __syncthreads();

    // ---------------- phase 4: softmax over neighbors (per head) ----------------
    {
        int h  = tid >> 5;       // 0..7
        int n0 = tid & 31;
        float s0 = scores_s[h * NBH + n0];
        float s1 = scores_s[h * NBH + n0 + 32];
        float m  = fmaxf(s0, s1);
        m = fmaxf(m, __shfl_xor(m, 1, 64));
        m = fmaxf(m, __shfl_xor(m, 2, 64));
        m = fmaxf(m, __shfl_xor(m, 4, 64));
        m = fmaxf(m, __shfl_xor(m, 8, 64));
        m = fmaxf(m, __shfl_xor(m, 16, 64));
        float e0 = expf(s0 - m);
        float e1 = expf(s1 - m);
        float sm = e0 + e1;
        sm += __shfl_xor(sm, 1, 64);
        sm += __shfl_xor(sm, 2, 64);
        sm += __shfl_xor(sm, 4, 64);
        sm += __shfl_xor(sm, 8, 64);
        sm += __shfl_xor(sm, 16, 64);
        float inv = 1.0f / sm;
        scores_s[h * NBH + n0]      = e0 * inv;
        scores_s[h * NBH + n0 + 32] = e1 * inv;
    }
    __syncthreads();

    // ---------------- phase 5: msg = attn . v (v still in registers) ----------------
    {
        int   head = j >> 4;
        float pm = 0.0f;
#pragma unroll
        for (int n = 0; n < 32; ++n)
            pm = fmaf(scores_s[head * NBH + nbase + n], vacc[n], pm);
        msg_part[nh * FF + j] = pm;
    }
    __syncthreads();
    if (tid < FF) msg_s[tid] = msg_part[tid] + msg_part[FF + tid];
    __syncthreads();

    // ---------------- phase 6: output projection + residual ----------------
    {
        float op = 0.0f;
        int   i0 = nh * 64;
#pragma unroll 4
        for (int i = 0; i < 64; ++i) {
            int ii = i0 + i;
            op = fmaf(msg_s[ii], Wo[ii * FF + j], op);
        }
        opart[nh * FF + j] = op;
    }
    __syncthreads();
    if (tid < FF)
        out[bao * FF + tid] = x_s[tid] + bo[tid] + opart[tid] + opart[FF + tid];
}

extern "C" void kernel_launch(void* const* d_in, const int* in_sizes, int n_in,
                              void* d_out, int out_size, void* d_ws, size_t ws_size,
                              hipStream_t stream) {
    // setup_inputs order:
    // 0:e (unused) 1:x 2:t (unused) 3:r_ij 4:f_ij 5:W_filt 6:b_filt
    // 7:Wq 8:Wk 9:Wv 10:Wo 11:bo 12:neighbors 13:neighbor_mask (bool -> int32)
    const float* x      = (const float*)d_in[1];
    const float* r_ij   = (const float*)d_in[3];
    const float* f_ij   = (const float*)d_in[4];
    const float* W_filt = (const float*)d_in[5];
    const float* b_filt = (const float*)d_in[6];
    const float* Wq     = (const float*)d_in[7];
    const float* Wk     = (const float*)d_in[8];
    const float* Wv     = (const float*)d_in[9];
    const float* Wo     = (const float*)d_in[10];
    const float* bo     = (const float*)d_in[11];
    const int*   nbr    = (const int*)d_in[12];
    const int*   msk    = (const int*)d_in[13];
    float* out = (float*)d_out;

    dim3 grid(BB * AA);   // 4096 blocks, one per atom
    dim3 block(256);
    hipLaunchKernelGGL(tdt_kernel, grid, block, 0, stream,
                       x, r_ij, f_ij, W_filt, b_filt, Wq, Wk, Wv, Wo, bo,
                       nbr, msk, out);
}

// Round 3
// 214.753 us; speedup vs baseline: 2.1496x; 2.1496x over previous
//
#include <hip/hip_runtime.h>
#include <math.h>

// Problem constants (match reference)
#define BB 8
#define AA 512
#define NBH 64
#define FF 128
#define GG 50
#define NH 8
#define DH 16
#define CUTOFF 5.0f

typedef __attribute__((ext_vector_type(8))) short bf16x8;  // 8 bf16 = 4 VGPRs
typedef __attribute__((ext_vector_type(4))) float f32x4;   // MFMA C/D

#define MST 136   // M_s (nbh) row stride in bf16: 272B -> 2-way LDS conflict (free)
#define FST 72    // f_s row stride in bf16: 144B -> 2-way (free)

// Packed B-fragment weight sizes (bf16 elements):
// layout dst[((c*S + s)*64 + lane)*8 + j] = W[s*32 + (lane>>4)*8 + j][c*16 + (lane&15)]
#define WK_ELEMS (8*4*64*8)   // 16384 (K=128 -> S=4)
#define WF_ELEMS (8*2*64*8)   // 8192  (K=64 pad -> S=2)

__device__ __forceinline__ short f2bf(float f) {
    union { float f; unsigned u; } v; v.f = f;
    unsigned r = v.u + 0x7fffu + ((v.u >> 16) & 1u);   // RNE
    return (short)(r >> 16);
}

// ---------------- prep: pack Wk, Wv, W_filt into MFMA B-fragment order ----------------
__global__ void prep_kernel(const float* __restrict__ Wk,
                            const float* __restrict__ Wv,
                            const float* __restrict__ Wf,
                            short* __restrict__ ws)
{
    int gid = blockIdx.x * blockDim.x + threadIdx.x;
    if (gid < 2 * WK_ELEMS) {
        const float* src = (gid < WK_ELEMS) ? Wk : Wv;
        int idx  = (gid < WK_ELEMS) ? gid : gid - WK_ELEMS;
        int jj   = idx & 7;
        int l    = (idx >> 3) & 63;
        int cs   = idx >> 9;
        int s    = cs & 3, c = cs >> 2;
        int k    = s * 32 + (l >> 4) * 8 + jj;
        int n    = c * 16 + (l & 15);
        ws[gid] = f2bf(src[k * FF + n]);
    } else if (gid < 2 * WK_ELEMS + WF_ELEMS) {
        int idx = gid - 2 * WK_ELEMS;
        int jj  = idx & 7;
        int l   = (idx >> 3) & 63;
        int cs  = idx >> 9;
        int s   = cs & 1, c = cs >> 1;
        int g   = s * 32 + (l >> 4) * 8 + jj;
        int n   = c * 16 + (l & 15);
        ws[gid] = (g < GG) ? f2bf(Wf[g * FF + n]) : (short)0;
    }
}

// ---------------- main: one block per atom, 4 waves ----------------
// Wave w owns neighbors [16w, 16w+16).
// MFMA 16x16x32 bf16 layouts (HW-verified, learn_hip m89):
//   A[m = lane&15][k = (lane>>4)*8 + j]     (8 contiguous bf16 -> ds_read_b128)
//   B[k = (lane>>4)*8 + j][n = lane&15]     (pre-packed by prep_kernel)
//   D: col = lane&15, row = (lane>>4)*4 + reg
__global__ __launch_bounds__(256, 3)
void tdt_main(const float* __restrict__ x,
              const float* __restrict__ r_ij,
              const float* __restrict__ f_ij,
              const float* __restrict__ b_filt,
              const float* __restrict__ Wq,
              const float* __restrict__ Wo,
              const float* __restrict__ bo,
              const int*   __restrict__ neighbors,
              const int*   __restrict__ nmask,
              const short* __restrict__ WkB,
              const short* __restrict__ WvB,
              const short* __restrict__ WfB,
              float* __restrict__ out)
{
    const int ba   = blockIdx.x;          // 0..4095
    const int b    = ba >> 9;
    const int tid  = threadIdx.x;
    const int lane = tid & 63;
    const int w    = tid >> 6;            // wave 0..3
    const int l15  = lane & 15;
    const int quad = lane >> 4;
    const int j    = tid & 127;
    const int nh   = tid >> 7;

    __shared__ short M_s[NBH * MST];      // nbh, bf16 row-major   (17.4 KB)
    __shared__ short f_s[NBH * FST];      // f_ij, bf16, K padded  ( 9.2 KB)
    __shared__ float x_s[FF];
    __shared__ float b_s[FF];
    __shared__ float bo_s[FF];
    __shared__ float C_s[NBH];
    __shared__ int   nbr_s[NBH];
    __shared__ int   mask_s[NBH];
    __shared__ float qpart[2 * FF];
    __shared__ float q_s[FF];
    __shared__ float scores_s[NH * NBH];  // reused in-place for attn
    __shared__ float msg_part[4 * FF];
    __shared__ float msg_s[FF];
    __shared__ float opart[2 * FF];

    const float* xb  = x + (size_t)b * AA * FF;
    const size_t bao = (size_t)ba;

    // ---------------- phase 0: cooperative loads ----------------
    if (tid < FF) {
        x_s[tid]  = x[bao * FF + tid];
        b_s[tid]  = b_filt[tid];
        bo_s[tid] = bo[tid];
    }
    if (tid < NBH) {
        float r = r_ij[bao * NBH + tid];
        float c = 0.5f * (cosf((float)M_PI * r * (1.0f / CUTOFF)) + 1.0f);
        C_s[tid]    = (r < CUTOFF) ? c : 0.0f;
        nbr_s[tid]  = neighbors[bao * NBH + tid];
        mask_s[tid] = nmask[bao * NBH + tid];
    }
    {
        const float* frow = f_ij + bao * (size_t)(NBH * GG);
        for (int idx = tid; idx < NBH * GG; idx += 256) {
            int n = idx / GG;
            int g = idx - n * GG;
            f_s[n * FST + g] = f2bf(frow[idx]);
        }
        for (int idx = tid; idx < NBH * (64 - GG); idx += 256) {  // zero-pad g=50..63
            int n = idx / (64 - GG);
            int g = GG + (idx - n * (64 - GG));
            f_s[n * FST + g] = 0;
        }
    }
    __syncthreads();

    // ---------------- phase 1a: q partial (vector fp32, 3% of FLOPs) ----------------
    {
        float qp = 0.0f;
        int   i0 = nh * 64;
#pragma unroll 8
        for (int i = 0; i < 64; ++i) {
            int ii = i0 + i;
            qp = fmaf(x_s[ii], Wq[ii * FF + j], qp);
        }
        qpart[nh * FF + j] = qp;
    }

    // ---------------- phase 1b: filter MFMA + modulate + gather -> M_s ----------------
    {
        bf16x8 fa0 = *(const bf16x8*)&f_s[(16 * w + l15) * FST + 0 * 32 + quad * 8];
        bf16x8 fa1 = *(const bf16x8*)&f_s[(16 * w + l15) * FST + 1 * 32 + quad * 8];
        f32x4 wacc[8];
#pragma unroll
        for (int c = 0; c < 8; ++c) {
            f32x4 z = {0.f, 0.f, 0.f, 0.f};
            bf16x8 b0 = *(const bf16x8*)&WfB[((c * 2 + 0) * 64 + lane) * 8];
            bf16x8 b1 = *(const bf16x8*)&WfB[((c * 2 + 1) * 64 + lane) * 8];
            z = __builtin_amdgcn_mfma_f32_16x16x32_bf16(fa0, b0, z, 0, 0, 0);
            z = __builtin_amdgcn_mfma_f32_16x16x32_bf16(fa1, b1, z, 0, 0, 0);
            wacc[c] = z;
        }
#pragma unroll
        for (int r = 0; r < 4; ++r) {
            int n = 16 * w + quad * 4 + r;
            float cn = C_s[n];
            const float* xrow = xb + (size_t)nbr_s[n] * FF;
#pragma unroll
            for (int c = 0; c < 8; ++c) {
                int col = c * 16 + l15;
                float val = (wacc[c][r] + b_s[col]) * cn * xrow[col];
                M_s[n * MST + col] = f2bf(val);
            }
        }
    }
    __syncthreads();

    // ---------------- phase 2: q combine + k/v MFMA (results stay in registers) ----
    if (tid < FF) q_s[tid] = qpart[tid] + qpart[FF + tid];

    f32x4 kacc[8], vacc[8];
    {
        bf16x8 ma[4];
#pragma unroll
        for (int s = 0; s < 4; ++s)
            ma[s] = *(const bf16x8*)&M_s[(16 * w + l15) * MST + s * 32 + quad * 8];
#pragma unroll
        for (int c = 0; c < 8; ++c) {
            f32x4 zk = {0.f, 0.f, 0.f, 0.f}, zv = {0.f, 0.f, 0.f, 0.f};
#pragma unroll
            for (int s = 0; s < 4; ++s) {
                bf16x8 bk = *(const bf16x8*)&WkB[((c * 4 + s) * 64 + lane) * 8];
                bf16x8 bv = *(const bf16x8*)&WvB[((c * 4 + s) * 64 + lane) * 8];
                zk = __builtin_amdgcn_mfma_f32_16x16x32_bf16(ma[s], bk, zk, 0, 0, 0);
                zv = __builtin_amdgcn_mfma_f32_16x16x32_bf16(ma[s], bv, zv, 0, 0, 0);
            }
            kacc[c] = zk; vacc[c] = zv;
        }
    }
    __syncthreads();   // q_s visible

    // ---------------- phase 3: scores[h][n] = q.k / 4 (head h == col-tile c) -------
    {
#pragma unroll
        for (int c = 0; c < 8; ++c) {
            float qv = q_s[c * 16 + l15];
#pragma unroll
            for (int r = 0; r < 4; ++r) {
                float s = kacc[c][r] * qv;
                s += __shfl_xor(s, 1, 64);
                s += __shfl_xor(s, 2, 64);
                s += __shfl_xor(s, 4, 64);
                s += __shfl_xor(s, 8, 64);
                if (l15 == 0) {
                    int n = 16 * w + quad * 4 + r;
                    float sc = s * 0.25f;            // 1/sqrt(DH)
                    if (!mask_s[n]) sc = -1e9f;
                    scores_s[c * NBH + n] = sc;
                }
            }
        }
    }
    __syncthreads();

    // ---------------- phase 4: softmax over neighbors (per head) ----------------
    {
        int h  = tid >> 5;
        int n0 = tid & 31;
        float s0 = scores_s[h * NBH + n0];
        float s1 = scores_s[h * NBH + n0 + 32];
        float m  = fmaxf(s0, s1);
        m = fmaxf(m, __shfl_xor(m, 1, 64));
        m = fmaxf(m, __shfl_xor(m, 2, 64));
        m = fmaxf(m, __shfl_xor(m, 4, 64));
        m = fmaxf(m, __shfl_xor(m, 8, 64));
        m = fmaxf(m, __shfl_xor(m, 16, 64));
        float e0 = expf(s0 - m);
        float e1 = expf(s1 - m);
        float sm = e0 + e1;
        sm += __shfl_xor(sm, 1, 64);
        sm += __shfl_xor(sm, 2, 64);
        sm += __shfl_xor(sm, 4, 64);
        sm += __shfl_xor(sm, 8, 64);
        sm += __shfl_xor(sm, 16, 64);
        float inv = 1.0f / sm;
        scores_s[h * NBH + n0]      = e0 * inv;
        scores_s[h * NBH + n0 + 32] = e1 * inv;
    }
    __syncthreads();

    // ---------------- phase 5: msg = attn . v (v in C-layout registers) ----------
    {
        float mp[8];
#pragma unroll
        for (int c = 0; c < 8; ++c) {
            float acc = 0.0f;
#pragma unroll
            for (int r = 0; r < 4; ++r) {
                int n = 16 * w + quad * 4 + r;
                acc = fmaf(scores_s[c * NBH + n], vacc[c][r], acc);
            }
            acc += __shfl_xor(acc, 16, 64);   // reduce across quads
            acc += __shfl_xor(acc, 32, 64);
            mp[c] = acc;
        }
        if (lane < 16) {
#pragma unroll
            for (int c = 0; c < 8; ++c)
                msg_part[w * FF + c * 16 + l15] = mp[c];
        }
    }
    __syncthreads();
    if (tid < FF)
        msg_s[tid] = msg_part[tid] + msg_part[FF + tid]
                   + msg_part[2 * FF + tid] + msg_part[3 * FF + tid];
    __syncthreads();

    // ---------------- phase 6: output projection + residual ----------------
    {
        float op = 0.0f;
        int   i0 = nh * 64;
#pragma unroll 8
        for (int i = 0; i < 64; ++i) {
            int ii = i0 + i;
            op = fmaf(msg_s[ii], Wo[ii * FF + j], op);
        }
        opart[nh * FF + j] = op;
    }
    __syncthreads();
    if (tid < FF)
        out[bao * FF + tid] = x_s[tid] + bo_s[tid] + opart[tid] + opart[FF + tid];
}

extern "C" void kernel_launch(void* const* d_in, const int* in_sizes, int n_in,
                              void* d_out, int out_size, void* d_ws, size_t ws_size,
                              hipStream_t stream) {
    // 0:e 1:x 2:t 3:r_ij 4:f_ij 5:W_filt 6:b_filt 7:Wq 8:Wk 9:Wv 10:Wo 11:bo
    // 12:neighbors 13:neighbor_mask (bool -> int32)
    const float* x      = (const float*)d_in[1];
    const float* r_ij   = (const float*)d_in[3];
    const float* f_ij   = (const float*)d_in[4];
    const float* W_filt = (const float*)d_in[5];
    const float* b_filt = (const float*)d_in[6];
    const float* Wq     = (const float*)d_in[7];
    const float* Wk     = (const float*)d_in[8];
    const float* Wv     = (const float*)d_in[9];
    const float* Wo     = (const float*)d_in[10];
    const float* bo     = (const float*)d_in[11];
    const int*   nbr    = (const int*)d_in[12];
    const int*   msk    = (const int*)d_in[13];
    float* out = (float*)d_out;

    short* ws = (short*)d_ws;   // 2*16384 + 8192 bf16 = 80 KB of scratch
    int prep_total = 2 * WK_ELEMS + WF_ELEMS;
    hipLaunchKernelGGL(prep_kernel, dim3((prep_total + 255) / 256), dim3(256), 0, stream,
                       Wk, Wv, W_filt, ws);
    hipLaunchKernelGGL(tdt_main, dim3(BB * AA), dim3(256), 0, stream,
                       x, r_ij, f_ij, b_filt, Wq, Wo, bo, nbr, msk,
                       ws, ws + WK_ELEMS, ws + 2 * WK_ELEMS, out);
}

// Round 4
// 166.921 us; speedup vs baseline: 2.7656x; 1.2866x over previous
//
#include <hip/hip_runtime.h>
#include <math.h>

// Problem constants (match reference)
#define BB 8
#define AA 512
#define NBH 64
#define FF 128
#define GG 50
#define NH 8
#define DH 16
#define CUTOFF 5.0f

typedef __attribute__((ext_vector_type(8))) short bf16x8;  // 8 bf16 = 4 VGPRs
typedef __attribute__((ext_vector_type(4))) float f32x4;   // MFMA C/D

#define MST 136   // M_s row stride (bf16): 272B -> ~2-way LDS aliasing (free)
#define FST 72    // f_s row stride (bf16): 144B -> ~2-way (free)

// Packed B-fragment sizes (bf16 elements):
// dst[((c*S + s)*64 + lane)*8 + j] = W[s*32 + (lane>>4)*8 + j][c*16 + (lane&15)]
#define W4_ELEMS (8*4*64*8)   // 16384 : K=128 matrices (Wk, Wv, Wq, Wo)
#define W2_ELEMS (8*2*64*8)   // 8192  : K=64 (W_filt zero-padded 50->64)

__device__ __forceinline__ short f2bf(float f) {
    union { float f; unsigned u; } v; v.f = f;
    unsigned r = v.u + 0x7fffu + ((v.u >> 16) & 1u);   // RNE
    return (short)(r >> 16);
}

// ---------------- prep: pack Wk,Wv,Wq,Wo (K=128) + W_filt (K=64 pad) ----------------
__global__ void prep_kernel(const float* __restrict__ Wk,
                            const float* __restrict__ Wv,
                            const float* __restrict__ Wq,
                            const float* __restrict__ Wo,
                            const float* __restrict__ Wf,
                            short* __restrict__ ws)
{
    int gid = blockIdx.x * blockDim.x + threadIdx.x;
    if (gid < 4 * W4_ELEMS) {
        int m = gid >> 14;                 // 16384 = 2^14
        const float* src = (m == 0) ? Wk : (m == 1) ? Wv : (m == 2) ? Wq : Wo;
        int idx = gid & (W4_ELEMS - 1);
        int jj  = idx & 7;
        int l   = (idx >> 3) & 63;
        int cs  = idx >> 9;
        int s   = cs & 3, c = cs >> 2;
        int k   = s * 32 + (l >> 4) * 8 + jj;
        int n   = c * 16 + (l & 15);
        ws[gid] = f2bf(src[k * FF + n]);
    } else if (gid < 4 * W4_ELEMS + W2_ELEMS) {
        int idx = gid - 4 * W4_ELEMS;
        int jj  = idx & 7;
        int l   = (idx >> 3) & 63;
        int cs  = idx >> 9;
        int s   = cs & 1, c = cs >> 1;
        int g   = s * 32 + (l >> 4) * 8 + jj;
        int n   = c * 16 + (l & 15);
        ws[gid] = (g < GG) ? f2bf(Wf[g * FF + n]) : (short)0;
    }
}

// ---------------- main: one block per atom, 4 waves ----------------
// Wave w owns col-tiles cg in {2w, 2w+1} (cols 32w..32w+31 == heads 2w,2w+1)
// for ALL 64 neighbors. B-fragment reads are disjoint across waves; the whole
// attention (scores/softmax/msg) for a head lives inside one wave -> no barrier.
// MFMA 16x16x32 bf16 layouts (HW-verified, learn_hip m89):
//   A[m = lane&15][k = (lane>>4)*8 + j]   B[k][n = lane&15]   D: col=lane&15, row=(lane>>4)*4+reg
__global__ __launch_bounds__(256, 4)
void tdt_main(const float* __restrict__ x,
              const float* __restrict__ r_ij,
              const float* __restrict__ f_ij,
              const float* __restrict__ b_filt,
              const float* __restrict__ bo,
              const int*   __restrict__ neighbors,
              const int*   __restrict__ nmask,
              const short* __restrict__ WkB,
              const short* __restrict__ WvB,
              const short* __restrict__ WqB,
              const short* __restrict__ WoB,
              const short* __restrict__ WfB,
              float* __restrict__ out)
{
    const int ba   = blockIdx.x;          // 0..4095
    const int b    = ba >> 9;
    const int tid  = threadIdx.x;
    const int lane = tid & 63;
    const int w    = tid >> 6;            // wave 0..3
    const int l15  = lane & 15;
    const int quad = lane >> 4;

    __shared__ short M_s[NBH * MST];      // modulated gathered messages (17.4 KB)
    __shared__ short f_s[NBH * FST];      // f_ij bf16, K zero-padded    ( 9.2 KB)
    __shared__ short x_bf[FF];
    __shared__ short msg_bf[FF];
    __shared__ float x_s[FF];
    __shared__ float C_s[NBH];
    __shared__ int   nbr_s[NBH];
    __shared__ int   mask_s[NBH];

    const float* xb  = x + (size_t)b * AA * FF;
    const size_t bao = (size_t)ba;

    // ---------------- phase 0: cooperative loads ----------------
    if (tid < FF) {
        float xv = x[bao * FF + tid];
        x_s[tid]  = xv;
        x_bf[tid] = f2bf(xv);
    }
    if (tid < NBH) {
        float r = r_ij[bao * NBH + tid];
        float c = 0.5f * (cosf((float)M_PI * r * (1.0f / CUTOFF)) + 1.0f);
        C_s[tid]    = (r < CUTOFF) ? c : 0.0f;
        nbr_s[tid]  = neighbors[bao * NBH + tid];
        mask_s[tid] = nmask[bao * NBH + tid];
    }
    {
        const float* frow = f_ij + bao * (size_t)(NBH * GG);
        for (int idx = tid; idx < NBH * GG; idx += 256) {
            int n = idx / GG;
            int g = idx - n * GG;
            f_s[n * FST + g] = f2bf(frow[idx]);
        }
        for (int idx = tid; idx < NBH * (64 - GG); idx += 256) {  // zero-pad g=50..63
            int n = idx / (64 - GG);
            int g = GG + (idx - n * (64 - GG));
            f_s[n * FST + g] = 0;
        }
    }
    __syncthreads();

    // ---------------- phase 1a: q via MFMA (A rows = broadcast x) ----------------
    float qv[2];
    {
        bf16x8 xa[4];
#pragma unroll
        for (int s = 0; s < 4; ++s)
            xa[s] = *(const bf16x8*)&x_bf[s * 32 + quad * 8];
#pragma unroll
        for (int ct = 0; ct < 2; ++ct) {
            int cg = 2 * w + ct;
            f32x4 z = {0.f, 0.f, 0.f, 0.f};
#pragma unroll
            for (int s = 0; s < 4; ++s) {
                bf16x8 bq = *(const bf16x8*)&WqB[((cg * 4 + s) * 64 + lane) * 8];
                z = __builtin_amdgcn_mfma_f32_16x16x32_bf16(xa[s], bq, z, 0, 0, 0);
            }
            qv[ct] = z[0];   // all rows identical; col = cg*16 + l15
        }
    }

    // ---------------- phase 1b: filter MFMA (all 64 nbh x my 32 cols) + modulate ----
    {
        f32x4 wacc[2][4];
        {
            bf16x8 fa[4][2];
#pragma unroll
            for (int mt = 0; mt < 4; ++mt)
#pragma unroll
                for (int s = 0; s < 2; ++s)
                    fa[mt][s] = *(const bf16x8*)&f_s[(16 * mt + l15) * FST + s * 32 + quad * 8];
#pragma unroll
            for (int ct = 0; ct < 2; ++ct) {
                int cg = 2 * w + ct;
                bf16x8 b0 = *(const bf16x8*)&WfB[((cg * 2 + 0) * 64 + lane) * 8];
                bf16x8 b1 = *(const bf16x8*)&WfB[((cg * 2 + 1) * 64 + lane) * 8];
#pragma unroll
                for (int mt = 0; mt < 4; ++mt) {
                    f32x4 z = {0.f, 0.f, 0.f, 0.f};
                    z = __builtin_amdgcn_mfma_f32_16x16x32_bf16(fa[mt][0], b0, z, 0, 0, 0);
                    z = __builtin_amdgcn_mfma_f32_16x16x32_bf16(fa[mt][1], b1, z, 0, 0, 0);
                    wacc[ct][mt] = z;
                }
            }
        }
        int   c0  = (2 * w + 0) * 16 + l15;
        int   c1  = (2 * w + 1) * 16 + l15;
        float bf0 = b_filt[c0];
        float bf1 = b_filt[c1];
#pragma unroll
        for (int mt = 0; mt < 4; ++mt) {
#pragma unroll
            for (int r = 0; r < 4; ++r) {
                int n = 16 * mt + quad * 4 + r;
                float cn = C_s[n];
                const float* xrow = xb + (size_t)nbr_s[n] * FF;
                M_s[n * MST + c0] = f2bf((wacc[0][mt][r] + bf0) * cn * xrow[c0]);
                M_s[n * MST + c1] = f2bf((wacc[1][mt][r] + bf1) * cn * xrow[c1]);
            }
        }
    }
    __syncthreads();

    // ---------------- phase 2-5: k/v MFMA + scores + softmax + msg, per head, barrier-free
#pragma unroll
    for (int ct = 0; ct < 2; ++ct) {
        int cg = 2 * w + ct;
        bf16x8 bk[4], bv[4];
#pragma unroll
        for (int s = 0; s < 4; ++s) {
            bk[s] = *(const bf16x8*)&WkB[((cg * 4 + s) * 64 + lane) * 8];
            bv[s] = *(const bf16x8*)&WvB[((cg * 4 + s) * 64 + lane) * 8];
        }
        f32x4 kacc[4], vacc[4];
#pragma unroll
        for (int mt = 0; mt < 4; ++mt) {
            f32x4 zk = {0.f, 0.f, 0.f, 0.f}, zv = {0.f, 0.f, 0.f, 0.f};
#pragma unroll
            for (int s = 0; s < 4; ++s) {
                bf16x8 ma = *(const bf16x8*)&M_s[(16 * mt + l15) * MST + s * 32 + quad * 8];
                zk = __builtin_amdgcn_mfma_f32_16x16x32_bf16(ma, bk[s], zk, 0, 0, 0);
                zv = __builtin_amdgcn_mfma_f32_16x16x32_bf16(ma, bv[s], zv, 0, 0, 0);
            }
            kacc[mt] = zk; vacc[mt] = zv;
        }
        // scores: reduce q.k over the 16 dims (lanes l15) of head cg
        float sc[4][4];
#pragma unroll
        for (int mt = 0; mt < 4; ++mt) {
#pragma unroll
            for (int r = 0; r < 4; ++r) {
                float s = kacc[mt][r] * qv[ct];
                s += __shfl_xor(s, 1, 64);
                s += __shfl_xor(s, 2, 64);
                s += __shfl_xor(s, 4, 64);
                s += __shfl_xor(s, 8, 64);
                int n = 16 * mt + quad * 4 + r;
                s *= 0.25f;                       // 1/sqrt(DH)
                if (!mask_s[n]) s = -1e9f;
                sc[mt][r] = s;
            }
        }
        // softmax over all 64 neighbors: 16 in-register + cross-quad shuffles
        float m = sc[0][0];
#pragma unroll
        for (int mt = 0; mt < 4; ++mt)
#pragma unroll
            for (int r = 0; r < 4; ++r) m = fmaxf(m, sc[mt][r]);
        m = fmaxf(m, __shfl_xor(m, 16, 64));
        m = fmaxf(m, __shfl_xor(m, 32, 64));
        float sum = 0.0f;
#pragma unroll
        for (int mt = 0; mt < 4; ++mt)
#pragma unroll
            for (int r = 0; r < 4; ++r) {
                sc[mt][r] = __expf(sc[mt][r] - m);
                sum += sc[mt][r];
            }
        sum += __shfl_xor(sum, 16, 64);
        sum += __shfl_xor(sum, 32, 64);
        float inv = 1.0f / sum;
        // msg[head cg][dim l15] = sum_n attn*v
        float acc = 0.0f;
#pragma unroll
        for (int mt = 0; mt < 4; ++mt)
#pragma unroll
            for (int r = 0; r < 4; ++r)
                acc = fmaf(sc[mt][r], vacc[mt][r], acc);
        acc += __shfl_xor(acc, 16, 64);
        acc += __shfl_xor(acc, 32, 64);
        if (quad == 0) msg_bf[cg * 16 + l15] = f2bf(acc * inv);
    }
    __syncthreads();

    // ---------------- phase 6: out = msg.Wo + x + bo (MFMA, broadcast-A) ----------
    {
        bf16x8 mga[4];
#pragma unroll
        for (int s = 0; s < 4; ++s)
            mga[s] = *(const bf16x8*)&msg_bf[s * 32 + quad * 8];
#pragma unroll
        for (int ct = 0; ct < 2; ++ct) {
            int cg = 2 * w + ct;
            f32x4 z = {0.f, 0.f, 0.f, 0.f};
#pragma unroll
            for (int s = 0; s < 4; ++s) {
                bf16x8 bw = *(const bf16x8*)&WoB[((cg * 4 + s) * 64 + lane) * 8];
                z = __builtin_amdgcn_mfma_f32_16x16x32_bf16(mga[s], bw, z, 0, 0, 0);
            }
            if (quad == 0) {
                int col = cg * 16 + l15;
                out[bao * FF + col] = z[0] + x_s[col] + bo[col];
            }
        }
    }
}

extern "C" void kernel_launch(void* const* d_in, const int* in_sizes, int n_in,
                              void* d_out, int out_size, void* d_ws, size_t ws_size,
                              hipStream_t stream) {
    // 0:e 1:x 2:t 3:r_ij 4:f_ij 5:W_filt 6:b_filt 7:Wq 8:Wk 9:Wv 10:Wo 11:bo
    // 12:neighbors 13:neighbor_mask (bool -> int32)
    const float* x      = (const float*)d_in[1];
    const float* r_ij   = (const float*)d_in[3];
    const float* f_ij   = (const float*)d_in[4];
    const float* W_filt = (const float*)d_in[5];
    const float* b_filt = (const float*)d_in[6];
    const float* Wq     = (const float*)d_in[7];
    const float* Wk     = (const float*)d_in[8];
    const float* Wv     = (const float*)d_in[9];
    const float* Wo     = (const float*)d_in[10];
    const float* bo     = (const float*)d_in[11];
    const int*   nbr    = (const int*)d_in[12];
    const int*   msk    = (const int*)d_in[13];
    float* out = (float*)d_out;

    short* ws = (short*)d_ws;  // 4*16384 + 8192 bf16 = 144 KB scratch
    short* WkB = ws;
    short* WvB = ws + W4_ELEMS;
    short* WqB = ws + 2 * W4_ELEMS;
    short* WoB = ws + 3 * W4_ELEMS;
    short* WfB = ws + 4 * W4_ELEMS;

    int prep_total = 4 * W4_ELEMS + W2_ELEMS;
    hipLaunchKernelGGL(prep_kernel, dim3((prep_total + 255) / 256), dim3(256), 0, stream,
                       Wk, Wv, Wq, Wo, W_filt, ws);
    hipLaunchKernelGGL(tdt_main, dim3(BB * AA), dim3(256), 0, stream,
                       x, r_ij, f_ij, b_filt, bo, nbr, msk,
                       WkB, WvB, WqB, WoB, WfB, out);
}